// Round 7
// baseline (174.617 us; speedup 1.0000x reference)
//
#include <hip/hip_runtime.h>
#include <hip/hip_bf16.h>

// S4D layer, round 7: planar complex layout + in-register chunk scan +
// device-detected identity-D_w fast path in gemm2.
//  prep           : A_bar, powtab (planar), bf16 weight casts (no permutation)
//  flag_kernel    : viol=OR(D_w != I)  (device-side identity detection)
//  gemm1_fused    : Bu = u @ Bw^T (MFMA dbuf) -> in-REGISTER chunk scan (shfl)
//                   -> H_loc bf16 + chunk-end E; emits u_bf
//  scan_carry_par : Kogge-Stone prefix over chunk carries (E -> P)
//  gemm2_fused    : identity path: y = Hfix @ Cw^T + u  (K=128, 2 steps + add)
//                   general path:  y = [u | Hfix] @ [Dw | Cw]^T (K=640)

#define D_MODEL 512
#define N2      128
#define BATCH   8
#define SEQ     4096
#define MTOT    (BATCH*SEQ)    // 32768
#define LC      16
#define NC      (SEQ/LC)       // 256

// ---- workspace byte offsets ----
#define OFFB_ABAR   0u            // 128 f32 planar: [n]=Ar, [64+n]=Ai
#define OFFB_POWTAB 512u          // 16*128 f32 planar
#define OFFB_VIOL   8704u         // int flag
#define OFFB_BWPB   16384u        // 128*512 bf16
#define OFFB_W2B    147456u       // 512*640 bf16
#define OFFB_E      1048576u      // 8*256*128 f32 planar (1 MB)
#define OFFB_P      2097152u      // 8*256*128 f32 planar (1 MB)
#define OFFB_HLOC   3145728u      // 32768*128 bf16 planar (8 MB)
#define OFFB_UBF    11534336u     // 32768*512 bf16 (32 MB)

typedef __bf16  bf16x8  __attribute__((ext_vector_type(8)));
typedef float   f32x4   __attribute__((ext_vector_type(4)));
typedef unsigned short ushort8 __attribute__((ext_vector_type(8)));

__device__ __forceinline__ unsigned short f2bf(float f) {
    union { float f; unsigned int u; } v; v.f = f;
    unsigned int r = v.u + 0x7fffu + ((v.u >> 16) & 1u);   // RNE
    return (unsigned short)(r >> 16);
}
__device__ __forceinline__ float bf2f(unsigned short s) {
    union { unsigned int u; float f; } v; v.u = ((unsigned int)s) << 16;
    return v.f;
}
__device__ __forceinline__ void gload_lds16(const void* g, void* l) {
    __builtin_amdgcn_global_load_lds(
        (const __attribute__((address_space(1))) void*)g,
        (__attribute__((address_space(3))) void*)l, 16, 0, 0);
}

// ---------------------------------------------------------------------------
// prep: planar A_bar / powtab, direct bf16 casts of weights, viol=0.
// ---------------------------------------------------------------------------
__global__ __launch_bounds__(256) void prep_kernel(
    const float* __restrict__ lar, const float* __restrict__ lai,
    const float* __restrict__ Bw,  const float* __restrict__ Cw,
    const float* __restrict__ Dw,
    float* __restrict__ abar, float* __restrict__ powtab, int* __restrict__ viol,
    unsigned short* __restrict__ Bwpb, unsigned short* __restrict__ W2b)
{
    int tid = blockIdx.x * blockDim.x + threadIdx.x;
    if (blockIdx.x == 0 && threadIdx.x == 0) *viol = 0;
    if (blockIdx.x == 0 && threadIdx.x < 64) {
        int n = threadIdx.x;
        float ar = -expf(lar[n]);
        float ai = lai[n];
        const float h = 0.5f;
        float nr = 1.f + h * ar, ni = h * ai;
        float dr = 1.f - h * ar, di = -h * ai;
        float den = dr * dr + di * di;
        float Ar = (nr * dr + ni * di) / den;
        float Ai = (ni * dr - nr * di) / den;
        abar[n] = Ar; abar[64 + n] = Ai;
        float pr = Ar, pi = Ai;
        for (int i = 0; i < LC; ++i) {            // powtab[i][n] = a^(i+1)
            powtab[i * 128 + n]      = pr;
            powtab[i * 128 + 64 + n] = pi;
            float npr = pr * Ar - pi * Ai;
            float npi = pr * Ai + pi * Ar;
            pr = npr; pi = npi;
        }
    }
    int stride = gridDim.x * blockDim.x;
    for (int idx = tid; idx < N2 * D_MODEL; idx += stride)
        Bwpb[idx] = f2bf(Bw[idx]);                // planar: no permutation
    for (int idx = tid; idx < D_MODEL * 640; idx += stride) {
        int d = idx / 640, k = idx % 640;
        float v = (k < D_MODEL) ? Dw[d * D_MODEL + k] : Cw[d * N2 + (k - D_MODEL)];
        W2b[idx] = f2bf(v);
    }
}

// flag: viol |= (Dw != identity)
__global__ __launch_bounds__(256) void flag_kernel(
    const float* __restrict__ Dw, int* __restrict__ viol)
{
    int idx = blockIdx.x * blockDim.x + threadIdx.x;
    int stride = gridDim.x * blockDim.x;
    int bad = 0;
    for (int i = idx; i < D_MODEL * D_MODEL; i += stride) {
        float expect = ((i / D_MODEL) == (i % D_MODEL)) ? 1.f : 0.f;
        bad |= (Dw[i] != expect);
    }
    if (bad) atomicOr(viol, 1);
}

// ---------------------------------------------------------------------------
// gemm1_fused: 64x128 tile, K=512, dbuf. Planar cols (0-63 re, 64-127 im).
// Waves: wm=(w>>1)*32 rows; wc=(w&1)*32; fragments f=0,1 re cols wc+f*16,
// f=2,3 im cols 64+wc+(f-2)*16 -> chain (re,im) live in the SAME lane.
// Epilogue: in-register chunk scan via __shfl_up, no LDS round-trip.
// ---------------------------------------------------------------------------
__global__ __launch_bounds__(256) void gemm1_fused(
    const float* __restrict__ u, const unsigned short* __restrict__ Bwpb,
    const float* __restrict__ abar,
    unsigned short* __restrict__ Hloc, float* __restrict__ E,
    unsigned short* __restrict__ u_bf)
{
    __shared__ __align__(16) char smem[49152];
    unsigned short* As0 = (unsigned short*)smem;            // 8 KB
    unsigned short* As1 = (unsigned short*)(smem + 8192);
    unsigned short* Bs0 = (unsigned short*)(smem + 16384);  // 16 KB
    unsigned short* Bs1 = (unsigned short*)(smem + 32768);

    const int tid  = threadIdx.x;
    const int lane = tid & 63;
    const int w    = tid >> 6;
    const int wm   = (w >> 1) * 32;
    const int wc   = (w & 1) * 32;
    const int m0   = blockIdx.x * 64;
    const int tr = tid >> 3, tc = tid & 7;

    f32x4 acc[2][4];
#pragma unroll
    for (int i = 0; i < 2; ++i)
#pragma unroll
        for (int f = 0; f < 4; ++f)
            acc[i][f] = (f32x4){0.f, 0.f, 0.f, 0.f};

    auto stage = [&](int t, unsigned short* Asb, unsigned short* Bsb) {
        const int k0 = t * 64;
#pragma unroll
        for (int q = 0; q < 4; ++q) {            // B: 128 rows x 64 k
            int r = q * 32 + tr;
            int cs = tc ^ (r & 7);
            gload_lds16(Bwpb + (size_t)r * D_MODEL + k0 + cs * 8,
                        (char*)Bsb + (q * 256 + tid) * 16);
        }
#pragma unroll
        for (int q = 0; q < 2; ++q) {            // A: 64 rows, f32->bf16 + ubf
            int r = q * 32 + tr;
            const float* src = u + (size_t)(m0 + r) * D_MODEL + k0 + tc * 8;
            float4 v0 = *(const float4*)src;
            float4 v1 = *(const float4*)(src + 4);
            ushort8 p;
            p[0] = f2bf(v0.x); p[1] = f2bf(v0.y); p[2] = f2bf(v0.z); p[3] = f2bf(v0.w);
            p[4] = f2bf(v1.x); p[5] = f2bf(v1.y); p[6] = f2bf(v1.z); p[7] = f2bf(v1.w);
            int cd = tc ^ (r & 7);
            *(ushort8*)((char*)Asb + r * 128 + cd * 16) = p;
            *(ushort8*)&u_bf[(size_t)(m0 + r) * D_MODEL + k0 + tc * 8] = p;
        }
    };
    auto compute = [&](const unsigned short* Asb, const unsigned short* Bsb) {
#pragma unroll
        for (int kk = 0; kk < 2; ++kk) {
            const int kb = kk * 64 + ((lane >> 4) << 4);
            bf16x8 a[2], b[4];
#pragma unroll
            for (int i = 0; i < 2; ++i) {
                int row = wm + i * 16 + (lane & 15);
                a[i] = *(const bf16x8*)((const char*)Asb + row * 128 + (kb ^ ((row & 7) << 4)));
            }
            const int rb = wc + (lane & 15);
            const int rowb[4] = {rb, rb + 16, rb + 64, rb + 80};
#pragma unroll
            for (int f = 0; f < 4; ++f) {
                int row = rowb[f];
                b[f] = *(const bf16x8*)((const char*)Bsb + row * 128 + (kb ^ ((row & 7) << 4)));
            }
#pragma unroll
            for (int i = 0; i < 2; ++i)
#pragma unroll
                for (int f = 0; f < 4; ++f)
                    acc[i][f] = __builtin_amdgcn_mfma_f32_16x16x32_bf16(a[i], b[f], acc[i][f], 0, 0, 0);
        }
    };

    unsigned short *Ac = As0, *Bc = Bs0, *An = As1, *Bn = Bs1;
    stage(0, Ac, Bc);
    for (int t = 0; t < 8; ++t) {
        __syncthreads();
        if (t + 1 < 8) stage(t + 1, An, Bn);
        compute(Ac, Bc);
        unsigned short* s;
        s = Ac; Ac = An; An = s;
        s = Bc; Bc = Bn; Bn = s;
    }

    // ---- epilogue: in-register local chunk scan (h0 = 0 per 16-row chunk) ----
    const int q = lane >> 4;                      // time quarter: t_loc = 4q+r
#pragma unroll
    for (int jj = 0; jj < 2; ++jj) {
        const int col = wc + jj * 16 + (lane & 15);
        float Ar = abar[col], Ai = abar[64 + col];
        float a2r = Ar * Ar - Ai * Ai,   a2i = 2.f * Ar * Ai;
        float a3r = a2r * Ar - a2i * Ai, a3i = a2r * Ai + a2i * Ar;
        float a4r = a2r * a2r - a2i * a2i, a4i = 2.f * a2r * a2i;
        float a8r = a4r * a4r - a4i * a4i, a8i = 2.f * a4r * a4i;
#pragma unroll
        for (int i = 0; i < 2; ++i) {
            float sr[4], si[4];
            sr[0] = acc[i][jj][0]; si[0] = acc[i][jj + 2][0];
#pragma unroll
            for (int r = 1; r < 4; ++r) {
                float xr = acc[i][jj][r], xi = acc[i][jj + 2][r];
                sr[r] = fmaf(Ar, sr[r-1], fmaf(-Ai, si[r-1], xr));
                si[r] = fmaf(Ar, si[r-1], fmaf( Ai, sr[r-1], xi));
            }
            // cross-quarter inclusive scan of (s3, a^4)
            float vr = sr[3], vi = si[3];
            float tr_ = __shfl_up(vr, 16), ti_ = __shfl_up(vi, 16);
            if (lane >= 16) {
                vr = fmaf(a4r, tr_, fmaf(-a4i, ti_, vr));
                vi = fmaf(a4r, ti_, fmaf( a4i, tr_, vi));
            }
            tr_ = __shfl_up(vr, 32); ti_ = __shfl_up(vi, 32);
            if (lane >= 32) {
                vr = fmaf(a8r, tr_, fmaf(-a8i, ti_, vr));
                vi = fmaf(a8r, ti_, fmaf( a8i, tr_, vi));
            }
            float cr = __shfl_up(vr, 16), ci = __shfl_up(vi, 16);
            if (lane < 16) { cr = 0.f; ci = 0.f; }
            // h_r = s_r + a^(r+1) * c
            float hr[4], hi[4];
            hr[0] = fmaf(Ar,  cr, fmaf(-Ai,  ci, sr[0]));
            hi[0] = fmaf(Ar,  ci, fmaf( Ai,  cr, si[0]));
            hr[1] = fmaf(a2r, cr, fmaf(-a2i, ci, sr[1]));
            hi[1] = fmaf(a2r, ci, fmaf( a2i, cr, si[1]));
            hr[2] = fmaf(a3r, cr, fmaf(-a3i, ci, sr[2]));
            hi[2] = fmaf(a3r, ci, fmaf( a3i, cr, si[2]));
            hr[3] = fmaf(a4r, cr, fmaf(-a4i, ci, sr[3]));
            hi[3] = fmaf(a4r, ci, fmaf( a4i, cr, si[3]));
            const int mrow = m0 + wm + 16 * i;    // chunk start row
#pragma unroll
            for (int r = 0; r < 4; ++r) {
                int trow = mrow + q * 4 + r;
                Hloc[(size_t)trow * 128 + col]      = f2bf(hr[r]);
                Hloc[(size_t)trow * 128 + 64 + col] = f2bf(hi[r]);
            }
            if (q == 3) {                          // chunk-end state
                int cg = mrow >> 4;                // = b*NC + c
                E[(size_t)cg * 128 + col]      = hr[3];
                E[(size_t)cg * 128 + 64 + col] = hi[3];
            }
        }
    }
}

// ---------------------------------------------------------------------------
// scan_carry_par: grid (8 batches, 8 n-groups); per wave 2 chains; planar E/P.
// ---------------------------------------------------------------------------
__global__ __launch_bounds__(256) void scan_carry_par(
    const float* __restrict__ E, const float* __restrict__ abar,
    float* __restrict__ P)
{
    const int b    = blockIdx.x;
    const int g0   = blockIdx.y * 8;
    const int wv   = threadIdx.x >> 6;
    const int lane = threadIdx.x & 63;

    for (int n = g0 + wv * 2; n < g0 + wv * 2 + 2; ++n) {
        float ar = abar[n], ai = abar[64 + n];
        for (int k = 0; k < 4; ++k) {     // aL = a^16
            float t = ar * ar - ai * ai;  ai = 2.f * ar * ai;  ar = t;
        }
        float pr[7], pi[7];               // aL^(2^k)
        pr[0] = ar; pi[0] = ai;
#pragma unroll
        for (int k = 1; k < 7; ++k) {
            pr[k] = pr[k-1] * pr[k-1] - pi[k-1] * pi[k-1];
            pi[k] = 2.f * pr[k-1] * pi[k-1];
        }
        int L = lane + 1;                 // aL^(lane+1)
        float wr = 1.f, wi = 0.f;
#pragma unroll
        for (int k = 0; k < 7; ++k) if ((L >> k) & 1) {
            float t = wr * pr[k] - wi * pi[k];
            wi = wr * pi[k] + wi * pr[k]; wr = t;
        }
        const float* Eb = E + (size_t)b * NC * 128;
        float* Pb = P + (size_t)b * NC * 128;
        float cr = 0.f, ci = 0.f;
        for (int s = 0; s < 4; ++s) {
            int idx = s * 64 + lane;
            float xr = Eb[(size_t)idx * 128 + n];
            float xi = Eb[(size_t)idx * 128 + 64 + n];
#pragma unroll
            for (int k = 0; k < 6; ++k) {
                int d = 1 << k;
                float tr_ = __shfl_up(xr, (unsigned)d);
                float ti_ = __shfl_up(xi, (unsigned)d);
                if (lane >= d) {
                    xr = fmaf(pr[k], tr_, fmaf(-pi[k], ti_, xr));
                    xi = fmaf(pr[k], ti_, fmaf(pi[k], tr_, xi));
                }
            }
            float gr = fmaf(wr, cr, fmaf(-wi, ci, xr));
            float gi = fmaf(wr, ci, fmaf(wi, cr, xi));
            float exr = __shfl_up(gr, 1u);
            float exi = __shfl_up(gi, 1u);
            if (lane == 0) { exr = cr; exi = ci; }
            Pb[(size_t)idx * 128 + n]      = exr;
            Pb[(size_t)idx * 128 + 64 + n] = exi;
            cr = __shfl(gr, 63);
            ci = __shfl(gi, 63);
        }
    }
}

// ---------------------------------------------------------------------------
// gemm2_fused: 128x128 tile. Identity-D_w path: K=128 (C-part) + u-add
// epilogue. General path: K=640. Fixup Hfix = Hloc + a^(i+1)*P during staging.
// ---------------------------------------------------------------------------
__global__ __launch_bounds__(256) void gemm2_fused(
    const unsigned short* __restrict__ ubf,
    const unsigned short* __restrict__ Hloc,
    const unsigned short* __restrict__ W2b,
    const float* __restrict__ P,
    const float* __restrict__ powtab,
    const int* __restrict__ viol,
    float* __restrict__ y)
{
    __shared__ __align__(16) char smem[65536];
    unsigned short* As0 = (unsigned short*)smem;
    unsigned short* As1 = (unsigned short*)(smem + 16384);
    unsigned short* Bs0 = (unsigned short*)(smem + 32768);
    unsigned short* Bs1 = (unsigned short*)(smem + 49152);

    const int tid  = threadIdx.x;
    const int lane = tid & 63;
    const int w    = tid >> 6;
    const int wm   = (w >> 1) * 64;
    const int wn   = (w & 1) * 64;
    const int m0   = blockIdx.x * 128;
    const int n0   = blockIdx.y * 128;
    const int tr = tid >> 3, tc = tid & 7;
    const int qq4 = lane >> 4;

    f32x4 acc[4][4];
#pragma unroll
    for (int i = 0; i < 4; ++i)
#pragma unroll
        for (int j = 0; j < 4; ++j)
            acc[i][j] = (f32x4){0.f, 0.f, 0.f, 0.f};

    auto stageB = [&](int k0, unsigned short* Bsb) {
#pragma unroll
        for (int q = 0; q < 4; ++q) {
            int r = q * 32 + tr;
            int cs = tc ^ (r & 7);
            gload_lds16(W2b + (size_t)(n0 + r) * 640 + k0 + cs * 8,
                        (char*)Bsb + (q * 256 + tid) * 16);
        }
    };
    auto stageA1 = [&](int k0, unsigned short* Asb) {     // u (bf16 DMA)
#pragma unroll
        for (int q = 0; q < 4; ++q) {
            int r = q * 32 + tr;
            int cs = tc ^ (r & 7);
            gload_lds16(ubf + (size_t)(m0 + r) * D_MODEL + k0 + cs * 8,
                        (char*)Asb + (q * 256 + tid) * 16);
        }
    };
    auto stageA2 = [&](int kk0, unsigned short* Asb) {    // Hfix, planar
        const bool isre = (kk0 == 0);
#pragma unroll
        for (int q = 0; q < 4; ++q) {
            int r = q * 32 + tr;
            int m = m0 + r;
            int cg = m >> 4;                              // b*NC + chunk
            int ii = m & 15;
            ushort8 hl = *(const ushort8*)&Hloc[(size_t)m * 128 + kk0 + tc * 8];
            const float* wb = powtab + ii * 128 + tc * 8;
            float4 w0 = *(const float4*)wb,        w1 = *(const float4*)(wb + 4);
            float4 x0 = *(const float4*)(wb + 64), x1 = *(const float4*)(wb + 68);
            const float* pb = P + (size_t)cg * 128 + tc * 8;
            float4 r0 = *(const float4*)pb,        r1 = *(const float4*)(pb + 4);
            float4 s0 = *(const float4*)(pb + 64), s1 = *(const float4*)(pb + 68);
            float wr[8] = {w0.x,w0.y,w0.z,w0.w, w1.x,w1.y,w1.z,w1.w};
            float wi[8] = {x0.x,x0.y,x0.z,x0.w, x1.x,x1.y,x1.z,x1.w};
            float prr[8] = {r0.x,r0.y,r0.z,r0.w, r1.x,r1.y,r1.z,r1.w};
            float pii[8] = {s0.x,s0.y,s0.z,s0.w, s1.x,s1.y,s1.z,s1.w};
            ushort8 o;
#pragma unroll
            for (int e = 0; e < 8; ++e) {
                float hv = bf2f(hl[e]);
                float fx = isre ? fmaf(wr[e], prr[e], fmaf(-wi[e], pii[e], hv))
                                : fmaf(wr[e], pii[e], fmaf( wi[e], prr[e], hv));
                o[e] = f2bf(fx);
            }
            int cd = tc ^ (r & 7);
            *(ushort8*)((char*)Asb + r * 128 + cd * 16) = o;
        }
    };
    auto compute = [&](const unsigned short* Asb, const unsigned short* Bsb) {
#pragma unroll
        for (int kk = 0; kk < 2; ++kk) {
            const int kb = kk * 64 + ((lane >> 4) << 4);
            bf16x8 a[4], b[4];
#pragma unroll
            for (int i = 0; i < 4; ++i) {
                int row = wm + i * 16 + (lane & 15);
                a[i] = *(const bf16x8*)((const char*)Asb + row * 128 + (kb ^ ((row & 7) << 4)));
            }
#pragma unroll
            for (int j = 0; j < 4; ++j) {
                int row = wn + j * 16 + (lane & 15);
                b[j] = *(const bf16x8*)((const char*)Bsb + row * 128 + (kb ^ ((row & 7) << 4)));
            }
#pragma unroll
            for (int i = 0; i < 4; ++i)
#pragma unroll
                for (int j = 0; j < 4; ++j)
                    acc[i][j] = __builtin_amdgcn_mfma_f32_16x16x32_bf16(a[i], b[j], acc[i][j], 0, 0, 0);
        }
    };

    const int isIdent = (*viol == 0);
    if (isIdent) {
        // ---- C-part only: K=128 in 2 steps ----
        stageB(512, Bs0); stageA2(0, As0);
        __syncthreads();
        stageB(576, Bs1); stageA2(64, As1);
        compute(As0, Bs0);
        __syncthreads();
        compute(As1, Bs1);
        __syncthreads();
        // ---- stage u tile (bf16, octet-swizzled) into smem[0..32KB) ----
        unsigned short* us = (unsigned short*)smem;
#pragma unroll
        for (int q2 = 0; q2 < 8; ++q2) {
            int row = q2 * 16 + (tid >> 4);
            int p   = tid & 15;
            int lo  = p ^ ((row >> 2) & 7);
            gload_lds16(ubf + (size_t)(m0 + row) * D_MODEL + n0 + lo * 8,
                        (char*)smem + (q2 * 256 + tid) * 16);
        }
        __syncthreads();
        // ---- y = acc + u ----
#pragma unroll
        for (int i = 0; i < 4; ++i)
#pragma unroll
            for (int j = 0; j < 4; ++j) {
                int cl  = wn + j * 16 + (lane & 15);
                int col = n0 + cl;
#pragma unroll
                for (int r = 0; r < 4; ++r) {
                    int row = wm + i * 16 + qq4 * 4 + r;
                    int ph  = (cl >> 3) ^ ((row >> 2) & 7);
                    float uv = bf2f(us[row * 128 + ph * 8 + (cl & 7)]);
                    y[(size_t)(m0 + row) * D_MODEL + col] = acc[i][j][r] + uv;
                }
            }
    } else {
        // ---- general: K=640 (u@Dw^T + Hfix@Cw^T) ----
        unsigned short *Ac = As0, *Bc = Bs0, *An = As1, *Bn = Bs1;
        stageB(0, Bc); stageA1(0, Ac);
        for (int t = 0; t < 10; ++t) {
            __syncthreads();
            if (t + 1 < 10) {
                int k0 = (t + 1) * 64;
                stageB(k0, Bn);
                if (k0 < D_MODEL) stageA1(k0, An);
                else              stageA2(k0 - D_MODEL, An);
            }
            compute(Ac, Bc);
            unsigned short* s;
            s = Ac; Ac = An; An = s;
            s = Bc; Bc = Bn; Bn = s;
        }
#pragma unroll
        for (int i = 0; i < 4; ++i)
#pragma unroll
            for (int j = 0; j < 4; ++j) {
                int col = n0 + wn + j * 16 + (lane & 15);
#pragma unroll
                for (int r = 0; r < 4; ++r) {
                    int row = m0 + wm + i * 16 + qq4 * 4 + r;
                    y[(size_t)row * D_MODEL + col] = acc[i][j][r];
                }
            }
    }
}

// ---------------------------------------------------------------------------
extern "C" void kernel_launch(void* const* d_in, const int* in_sizes, int n_in,
                              void* d_out, int out_size, void* d_ws, size_t ws_size,
                              hipStream_t stream)
{
    const float* u   = (const float*)d_in[0];
    const float* lar = (const float*)d_in[1];
    const float* lai = (const float*)d_in[2];
    const float* Bw  = (const float*)d_in[3];
    const float* Cw  = (const float*)d_in[4];
    const float* Dw  = (const float*)d_in[5];
    float* y = (float*)d_out;
    char* ws = (char*)d_ws;

    float*          abar   = (float*)(ws + OFFB_ABAR);
    float*          powtab = (float*)(ws + OFFB_POWTAB);
    int*            viol   = (int*)(ws + OFFB_VIOL);
    unsigned short* Bwpb   = (unsigned short*)(ws + OFFB_BWPB);
    unsigned short* W2b    = (unsigned short*)(ws + OFFB_W2B);
    float*          E      = (float*)(ws + OFFB_E);
    float*          P      = (float*)(ws + OFFB_P);
    unsigned short* Hloc   = (unsigned short*)(ws + OFFB_HLOC);
    unsigned short* u_bf   = (unsigned short*)(ws + OFFB_UBF);

    hipLaunchKernelGGL(prep_kernel, dim3(128), dim3(256), 0, stream,
                       lar, lai, Bw, Cw, Dw, abar, powtab, viol, Bwpb, W2b);
    hipLaunchKernelGGL(flag_kernel, dim3(64), dim3(256), 0, stream, Dw, viol);
    hipLaunchKernelGGL(gemm1_fused, dim3(MTOT / 64), dim3(256), 0, stream,
                       u, Bwpb, abar, Hloc, E, u_bf);
    hipLaunchKernelGGL(scan_carry_par, dim3(8, 8), dim3(256), 0, stream,
                       E, abar, P);
    hipLaunchKernelGGL(gemm2_fused, dim3(MTOT / 128, D_MODEL / 128),
                       dim3(256), 0, stream,
                       u_bf, Hloc, W2b, P, powtab, viol, y);
}